// Round 1
// 6673.451 us; speedup vs baseline: 1.0977x; 1.0977x over previous
//
#include <hip/hip_runtime.h>

// NeuralODE fused persistent kernel v6 (MI355X / gfx950).
// v5 -> v6: software-pipelined stage structure. Each RK4 stage is now two
// fused halves:
//   GEMM2half: k = h@W2 (96 MFMA) with the k hi/lo split+LDS-write fused in.
//   GEMM1half: per-jt {6-MFMA U[jt] chain; S/P1 update; tanh; split; h-write}
//              -> tanh/split VALU of jt overlaps MFMAs of jt+1.
// U[16] (64 regs) is consumed inside the iteration and eliminated.
// Packed v_cvt_pkrtz_f16_f32 replaces scalar cvt chains in all hi/lo splits.
// LDS layout, fences, and numerics (split-precision f16 MFMA) unchanged.

typedef _Float16 f16;
typedef _Float16 f16x4 __attribute__((ext_vector_type(4)));
typedef _Float16 f16x8 __attribute__((ext_vector_type(8)));
typedef float    f32x4 __attribute__((ext_vector_type(4)));

#define MFMA(a, b, c) __builtin_amdgcn_mfma_f32_16x16x32_f16((a), (b), (c), 0, 0, 0)

// Wave-local LDS exchange point: drain own DS ops + forbid compiler reordering.
static __device__ __forceinline__ void wave_exchange_fence() {
    __threadfence_block();
    __builtin_amdgcn_wave_barrier();
}

static __device__ __forceinline__ float fast_tanh(float x) {
    // 1 - 2/(1+exp2(2*log2e*x)); e=inf -> rcp(inf)=0 -> 1.0 (safe)
    float e = __builtin_amdgcn_exp2f(x * 2.885390081777927f);
    float r = __builtin_amdgcn_rcpf(e + 1.0f);
    return __builtin_fmaf(-2.0f, r, 1.0f);
}

// Compensated f32 -> (f16 hi, f16 lo) split of 4 values using packed rtz cvt.
// hi = rtz(t); lo = f16(t - hi) captures the residual exactly enough for the
// 3-term split-MFMA scheme (same accuracy class as the scalar-RNE version).
static __device__ __forceinline__ void split4(float t0, float t1, float t2, float t3,
                                              f16x4* hv, f16x4* lv) {
    auto h01 = __builtin_amdgcn_cvt_pkrtz(t0, t1);
    auto h23 = __builtin_amdgcn_cvt_pkrtz(t2, t3);
    float l0 = t0 - (float)h01[0], l1 = t1 - (float)h01[1];
    float l2 = t2 - (float)h23[0], l3 = t3 - (float)h23[1];
    auto s01 = __builtin_amdgcn_cvt_pkrtz(l0, l1);
    auto s23 = __builtin_amdgcn_cvt_pkrtz(l2, l3);
    f16x4 h, l;
    h[0] = h01[0]; h[1] = h01[1]; h[2] = h23[0]; h[3] = h23[1];
    l[0] = s01[0]; l[1] = s01[1]; l[2] = s23[0]; l[3] = s23[1];
    *hv = h; *lv = l;
}

__global__ __launch_bounds__(256, 1) void node_fused(
    const float* __restrict__ y0g, const float* __restrict__ tg,
    const float* __restrict__ W1,  const float* __restrict__ b1,
    const float* __restrict__ W2,  const float* __restrict__ b2,
    const float* __restrict__ Wfc, const float* __restrict__ bfc,
    float* __restrict__ out)
{
    // ---- LDS: 155648 B total ----
    __shared__ __align__(16) f16 w1loL[16 * 2 * 64 * 8];   // 32 KB  A-frags of W1lo
    __shared__ __align__(16) f16 w2loL[4 * 8 * 64 * 8];    // 32 KB  A-frags of W2lo
    __shared__ __align__(16) f16 wfcL [2 * 2 * 64 * 8];    // 4 KB   A-frags of Wfc (f16)
    __shared__ __align__(16) f16 hhiB[4 * 16 * 264];       // 33 KB  per-wave h-hi
    __shared__ __align__(16) f16 hloB[4 * 16 * 264];       // 33 KB  per-wave h-lo
    __shared__ __align__(16) f16 khiB[4 * 16 * 72];        // 9 KB   per-wave k-hi
    __shared__ __align__(16) f16 kloB[4 * 16 * 72];        // 9 KB   per-wave k-lo

    const int tid  = (int)threadIdx.x;
    const int wid  = tid >> 6;
    const int lane = tid & 63;
    const int q    = lane >> 4;   // quad 0..3
    const int c    = lane & 15;   // lane-in-16 (row)
    const int R0   = (int)blockIdx.x * 64 + wid * 16;

    f16* __restrict__ hhi = &hhiB[wid * 16 * 264];
    f16* __restrict__ hlo = &hloB[wid * 16 * 264];
    f16* __restrict__ khi = &khiB[wid * 16 * 72];
    f16* __restrict__ klo = &kloB[wid * 16 * 72];

    // ---------------- hi-weight A-fragments in VGPRs ----------------
    // A-layout (16x16x32): lane holds A[m = tile*16 + c][k = ks*32 + q*8 + j]
    f16x8 w1a[16][2];   // W1T hi
#pragma unroll
    for (int jt = 0; jt < 16; ++jt)
#pragma unroll
        for (int ks = 0; ks < 2; ++ks)
#pragma unroll
            for (int j = 0; j < 8; ++j)
                w1a[jt][ks][j] = (f16)W1[(ks * 32 + q * 8 + j) * 256 + jt * 16 + c];

    f16x8 w2a[4][8];    // W2T hi
#pragma unroll
    for (int dt = 0; dt < 4; ++dt)
#pragma unroll
        for (int ks = 0; ks < 8; ++ks)
#pragma unroll
            for (int j = 0; j < 8; ++j)
                w2a[dt][ks][j] = (f16)W2[(ks * 32 + q * 8 + j) * 64 + dt * 16 + c];

    // ---------------- lo-weight A-fragments -> LDS (split across waves) ----------------
    for (int jt = wid * 4; jt < wid * 4 + 4; ++jt)
        for (int ks = 0; ks < 2; ++ks)
            for (int j = 0; j < 8; ++j) {
                float w = W1[(ks * 32 + q * 8 + j) * 256 + jt * 16 + c];
                f16 hi = (f16)w;
                w1loL[((jt * 2 + ks) * 64 + lane) * 8 + j] = (f16)(w - (float)hi);
            }
    {
        int dt = wid;
        for (int ks = 0; ks < 8; ++ks)
            for (int j = 0; j < 8; ++j) {
                float w = W2[(ks * 32 + q * 8 + j) * 64 + dt * 16 + c];
                f16 hi = (f16)w;
                w2loL[((dt * 8 + ks) * 64 + lane) * 8 + j] = (f16)(w - (float)hi);
            }
    }
    if (wid == 0)
        for (int ot = 0; ot < 2; ++ot)
            for (int ks = 0; ks < 2; ++ks)
                for (int j = 0; j < 8; ++j)
                    wfcL[((ot * 2 + ks) * 64 + lane) * 8 + j] =
                        (f16)Wfc[(ks * 32 + q * 8 + j) * 32 + ot * 16 + c];
    __syncthreads();   // the only real barrier: lo-weights become read-only after this

    // biases to registers
    f32x4 b1v[16], b2v[4], bfcv[2];
#pragma unroll
    for (int jt = 0; jt < 16; ++jt)
#pragma unroll
        for (int r = 0; r < 4; ++r) b1v[jt][r] = b1[jt * 16 + 4 * q + r];
#pragma unroll
    for (int dt = 0; dt < 4; ++dt)
#pragma unroll
        for (int r = 0; r < 4; ++r) b2v[dt][r] = b2[dt * 16 + 4 * q + r];
#pragma unroll
    for (int ot = 0; ot < 2; ++ot)
#pragma unroll
        for (int r = 0; r < 4; ++r) bfcv[ot][r] = bfc[ot * 16 + 4 * q + r];

    // ---------------- init from y0 (split hi+lo) ----------------
    f16x8 y0hi[2], y0lo[2];
#pragma unroll
    for (int ks = 0; ks < 2; ++ks)
#pragma unroll
        for (int j = 0; j < 8; ++j) {
            float v = y0g[(R0 + c) * 64 + ks * 32 + q * 8 + j];
            f16 hi = (f16)v;
            y0hi[ks][j] = hi;
            y0lo[ks][j] = (f16)(v - (float)hi);
        }

    f32x4 P1[16];
#pragma unroll
    for (int jt = 0; jt < 16; ++jt) {
        f32x4 cc = b1v[jt];
#pragma unroll
        for (int ks = 0; ks < 2; ++ks) {
            f16x8 alo = *reinterpret_cast<const f16x8*>(&w1loL[((jt * 2 + ks) * 64 + lane) * 8]);
            cc = MFMA(w1a[jt][ks], y0hi[ks], cc);
            cc = MFMA(w1a[jt][ks], y0lo[ks], cc);
            cc = MFMA(alo,         y0hi[ks], cc);
        }
        P1[jt] = cc;
    }
    f32x4 pfc[2];
#pragma unroll
    for (int ot = 0; ot < 2; ++ot) {
        f32x4 z = {0.f, 0.f, 0.f, 0.f};
#pragma unroll
        for (int ks = 0; ks < 2; ++ks) {
            f16x8 wa = *reinterpret_cast<const f16x8*>(&wfcL[((ot * 2 + ks) * 64 + lane) * 8]);
            z = MFMA(wa, y0hi[ks], z);
            z = MFMA(wa, y0lo[ks], z);
        }
        pfc[ot] = z;
    }
#pragma unroll
    for (int ot = 0; ot < 2; ++ot) {
        f32x4 v = pfc[ot] + bfcv[ot];
        *reinterpret_cast<f32x4*>(&out[(size_t)(R0 + c) * 32 + ot * 16 + 4 * q]) = v;
    }

    f32x4 dy[4];
#pragma unroll
    for (int dt = 0; dt < 4; ++dt) dy[dt] = f32x4{0.f, 0.f, 0.f, 0.f};
    f32x4 S[16];   // RK4 combination accumulator (assigned by mode-0 stage)

    // ---- bootstrap: h1 = tanh(P1) into LDS (consumed by first GEMM2half) ----
#pragma unroll
    for (int jt = 0; jt < 16; ++jt) {
        float t0 = fast_tanh(P1[jt][0]), t1 = fast_tanh(P1[jt][1]);
        float t2 = fast_tanh(P1[jt][2]), t3 = fast_tanh(P1[jt][3]);
        f16x4 hv, lv;
        split4(t0, t1, t2, t3, &hv, &lv);
        *reinterpret_cast<f16x4*>(&hhi[c * 264 + jt * 16 + 4 * q]) = hv;
        *reinterpret_cast<f16x4*>(&hlo[c * 264 + jt * 16 + 4 * q]) = lv;
    }
    wave_exchange_fence();

    float hh = 0.f, ch = 0.f, c6 = 0.f;

    // GEMM2half: kT = hhi@W2hi + hlo@W2hi + hhi@W2lo + b2; dy += cw*k;
    // split k -> LDS. Ends with the k-exchange fence.
    auto gemm2half = [&](float cw) {
        f32x4 ka[4];
#pragma unroll
        for (int dt = 0; dt < 4; ++dt) ka[dt] = b2v[dt];
#pragma unroll
        for (int ks = 0; ks < 8; ++ks) {
            f16x8 bhi = *reinterpret_cast<const f16x8*>(&hhi[c * 264 + ks * 32 + q * 8]);
            f16x8 blo = *reinterpret_cast<const f16x8*>(&hlo[c * 264 + ks * 32 + q * 8]);
#pragma unroll
            for (int dt = 0; dt < 4; ++dt) {
                f16x8 alo = *reinterpret_cast<const f16x8*>(&w2loL[((dt * 8 + ks) * 64 + lane) * 8]);
                ka[dt] = MFMA(w2a[dt][ks], bhi, ka[dt]);
                ka[dt] = MFMA(w2a[dt][ks], blo, ka[dt]);
                ka[dt] = MFMA(alo,          bhi, ka[dt]);
            }
        }
#pragma unroll
        for (int dt = 0; dt < 4; ++dt) {
            dy[dt] += ka[dt] * cw;
            f16x4 hv, lv;
            split4(ka[dt][0], ka[dt][1], ka[dt][2], ka[dt][3], &hv, &lv);
            *reinterpret_cast<f16x4*>(&khi[c * 72 + dt * 16 + 4 * q]) = hv;
            *reinterpret_cast<f16x4*>(&klo[c * 72 + dt * 16 + 4 * q]) = lv;
        }
        wave_exchange_fence();
    };

    // GEMM1half (fused): per jt, 6-MFMA U chain -> S/P1 update -> tanh -> split
    // -> write next-stage h. The VALU tail of jt overlaps the MFMAs of jt+1.
    // mode 0: S  = z;      a = P1 + carg*z         (stage 1)
    // mode 1: S += w*z;    a = P1 + carg*z         (stages 2,3)
    // mode 2: S += z; P1 += c6*S; a = P1           (stage 4 / substep close)
    auto gemm1half = [&](float carg, float w, int mode) {
        f16x8 kh0 = *reinterpret_cast<const f16x8*>(&khi[c * 72 + q * 8]);
        f16x8 kh1 = *reinterpret_cast<const f16x8*>(&khi[c * 72 + 32 + q * 8]);
        f16x8 kl0 = *reinterpret_cast<const f16x8*>(&klo[c * 72 + q * 8]);
        f16x8 kl1 = *reinterpret_cast<const f16x8*>(&klo[c * 72 + 32 + q * 8]);
#pragma unroll
        for (int jt = 0; jt < 16; ++jt) {
            f16x8 a0 = *reinterpret_cast<const f16x8*>(&w1loL[((jt * 2 + 0) * 64 + lane) * 8]);
            f16x8 a1 = *reinterpret_cast<const f16x8*>(&w1loL[((jt * 2 + 1) * 64 + lane) * 8]);
            f32x4 z = {0.f, 0.f, 0.f, 0.f};
            z = MFMA(w1a[jt][0], kh0, z);
            z = MFMA(w1a[jt][0], kl0, z);
            z = MFMA(a0,         kh0, z);
            z = MFMA(w1a[jt][1], kh1, z);
            z = MFMA(w1a[jt][1], kl1, z);
            z = MFMA(a1,         kh1, z);
            float a0f, a1f, a2f, a3f;
            if (mode == 0) {
                S[jt] = z;
            } else if (mode == 1) {
                S[jt] += z * w;
            } else {
                S[jt] += z;
                P1[jt] += S[jt] * c6;
            }
            if (mode == 2) {
                a0f = P1[jt][0]; a1f = P1[jt][1]; a2f = P1[jt][2]; a3f = P1[jt][3];
            } else {
                a0f = __builtin_fmaf(carg, z[0], P1[jt][0]);
                a1f = __builtin_fmaf(carg, z[1], P1[jt][1]);
                a2f = __builtin_fmaf(carg, z[2], P1[jt][2]);
                a3f = __builtin_fmaf(carg, z[3], P1[jt][3]);
            }
            float t0 = fast_tanh(a0f), t1 = fast_tanh(a1f);
            float t2 = fast_tanh(a2f), t3 = fast_tanh(a3f);
            f16x4 hv, lv;
            split4(t0, t1, t2, t3, &hv, &lv);
            *reinterpret_cast<f16x4*>(&hhi[c * 264 + jt * 16 + 4 * q]) = hv;
            *reinterpret_cast<f16x4*>(&hlo[c * 264 + jt * 16 + 4 * q]) = lv;
        }
        wave_exchange_fence();
    };

#pragma unroll 1
    for (int ti = 0; ti < 49; ++ti) {
        float dtv = tg[ti + 1] - tg[ti];
        hh = dtv * 0.125f;
        ch = 0.5f * hh;
        c6 = hh * (1.0f / 6.0f);
#pragma unroll 1
        for (int sub = 0; sub < 8; ++sub) {
            gemm2half(c6);            // k1 from h1
            gemm1half(ch, 1.0f, 0);   // U1; h2 = tanh(P1 + ch*U1); S = U1
            gemm2half(c6 * 2.0f);     // k2
            gemm1half(ch, 2.0f, 1);   // U2; h3; S += 2*U2
            gemm2half(c6 * 2.0f);     // k3
            gemm1half(hh, 2.0f, 1);   // U3; h4; S += 2*U3
            gemm2half(c6);            // k4
            gemm1half(0.0f, 1.0f, 2); // U4; S += U4; P1 += c6*S; h1' = tanh(P1)
        }
        // ---- interval epilogue: pfc += dy @ Wfc (dy split hi+lo), emit row ----
#pragma unroll
        for (int dt = 0; dt < 4; ++dt) {
            f16x4 hv, lv;
            split4(dy[dt][0], dy[dt][1], dy[dt][2], dy[dt][3], &hv, &lv);
            *reinterpret_cast<f16x4*>(&khi[c * 72 + dt * 16 + 4 * q]) = hv;
            *reinterpret_cast<f16x4*>(&klo[c * 72 + dt * 16 + 4 * q]) = lv;
            dy[dt] = f32x4{0.f, 0.f, 0.f, 0.f};
        }
        wave_exchange_fence();
        {
            f16x8 dh0 = *reinterpret_cast<const f16x8*>(&khi[c * 72 + q * 8]);
            f16x8 dh1 = *reinterpret_cast<const f16x8*>(&khi[c * 72 + 32 + q * 8]);
            f16x8 dl0 = *reinterpret_cast<const f16x8*>(&klo[c * 72 + q * 8]);
            f16x8 dl1 = *reinterpret_cast<const f16x8*>(&klo[c * 72 + 32 + q * 8]);
#pragma unroll
            for (int ot = 0; ot < 2; ++ot) {
                f16x8 wa0 = *reinterpret_cast<const f16x8*>(&wfcL[((ot * 2 + 0) * 64 + lane) * 8]);
                f16x8 wa1 = *reinterpret_cast<const f16x8*>(&wfcL[((ot * 2 + 1) * 64 + lane) * 8]);
                pfc[ot] = MFMA(wa0, dh0, pfc[ot]);
                pfc[ot] = MFMA(wa0, dl0, pfc[ot]);
                pfc[ot] = MFMA(wa1, dh1, pfc[ot]);
                pfc[ot] = MFMA(wa1, dl1, pfc[ot]);
            }
        }
        wave_exchange_fence();  // drain epilogue k-reads before next gemm2half k-writes
        size_t base = (size_t)(ti + 1) * (16384 * 32);
#pragma unroll
        for (int ot = 0; ot < 2; ++ot) {
            f32x4 v = pfc[ot] + bfcv[ot];
            *reinterpret_cast<f32x4*>(&out[base + (size_t)(R0 + c) * 32 + ot * 16 + 4 * q]) = v;
        }
    }
}

extern "C" void kernel_launch(void* const* d_in, const int* in_sizes, int n_in,
                              void* d_out, int out_size, void* d_ws, size_t ws_size,
                              hipStream_t stream) {
    (void)in_sizes; (void)n_in; (void)d_ws; (void)ws_size; (void)out_size;
    const float* y0  = (const float*)d_in[0];
    const float* t   = (const float*)d_in[1];
    const float* W1  = (const float*)d_in[2];
    const float* b1  = (const float*)d_in[3];
    const float* W2  = (const float*)d_in[4];
    const float* b2  = (const float*)d_in[5];
    const float* Wfc = (const float*)d_in[6];
    const float* bfc = (const float*)d_in[7];
    float* out = (float*)d_out;
    // 256 blocks x 256 threads: 4 waves x 16 rows per block, 1 block/CU (152 KB LDS)
    node_fused<<<dim3(256), dim3(256), 0, stream>>>(y0, t, W1, b1, W2, b2, Wfc, bfc, out);
}

// Round 2
// 4878.086 us; speedup vs baseline: 1.5017x; 1.3680x over previous
//
#include <hip/hip_runtime.h>

// NeuralODE fused persistent kernel v7 (MI355X / gfx950).
// v6 -> v7: 8 waves/block (512 thr), 2 waves/SIMD. Each 16-row group is owned
// by a WAVE PAIR:
//   GEMM1 (U = W1T@k) + tanh + h-split: split by H  (half 0: jt 0..7, half 1: jt 8..15)
//   GEMM2 (k = W2T@h) + k-split:        split by D  (half 0: dt 0..1, half 1: dt 2..3)
// h/k LDS buffers are pair-shared; 2 __syncthreads() per stage.
// S[16] eliminated via linearity: P1 += W1T@(c6*(k1+2k2+2k3+k4)) -> accumulate
// ksum in GEMM2, one extra-operand GEMM at stage 4; dy += c6*ksum per substep.
// Per-wave state: w1a 64 + w2a 64 (AGPR) + P1 32 + ~50 VGPR -> fits 2 waves/SIMD.

typedef _Float16 f16;
typedef _Float16 f16x4 __attribute__((ext_vector_type(4)));
typedef _Float16 f16x8 __attribute__((ext_vector_type(8)));
typedef float    f32x4 __attribute__((ext_vector_type(4)));

#define MFMA(a, b, c) __builtin_amdgcn_mfma_f32_16x16x32_f16((a), (b), (c), 0, 0, 0)

static __device__ __forceinline__ float fast_tanh(float x) {
    // 1 - 2/(1+exp2(2*log2e*x)); e=inf -> rcp(inf)=0 -> 1.0 (safe)
    float e = __builtin_amdgcn_exp2f(x * 2.885390081777927f);
    float r = __builtin_amdgcn_rcpf(e + 1.0f);
    return __builtin_fmaf(-2.0f, r, 1.0f);
}

// f32 -> (f16 hi, f16 lo) compensated split of 4 values via packed rtz cvt.
static __device__ __forceinline__ void split4(float t0, float t1, float t2, float t3,
                                              f16x4* hv, f16x4* lv) {
    auto h01 = __builtin_amdgcn_cvt_pkrtz(t0, t1);
    auto h23 = __builtin_amdgcn_cvt_pkrtz(t2, t3);
    float l0 = t0 - (float)h01[0], l1 = t1 - (float)h01[1];
    float l2 = t2 - (float)h23[0], l3 = t3 - (float)h23[1];
    auto s01 = __builtin_amdgcn_cvt_pkrtz(l0, l1);
    auto s23 = __builtin_amdgcn_cvt_pkrtz(l2, l3);
    f16x4 h, l;
    h[0] = h01[0]; h[1] = h01[1]; h[2] = h23[0]; h[3] = h23[1];
    l[0] = s01[0]; l[1] = s01[1]; l[2] = s23[0]; l[3] = s23[1];
    *hv = h; *lv = l;
}

__global__ __launch_bounds__(512, 2) void node_fused(
    const float* __restrict__ y0g, const float* __restrict__ tg,
    const float* __restrict__ W1,  const float* __restrict__ b1,
    const float* __restrict__ W2,  const float* __restrict__ b2,
    const float* __restrict__ Wfc, const float* __restrict__ bfc,
    float* __restrict__ out)
{
    // ---- LDS: 155648 B total ----
    __shared__ __align__(16) f16 w1loL[16 * 2 * 64 * 8];   // 32 KB  A-frags of W1lo
    __shared__ __align__(16) f16 w2loL[4 * 8 * 64 * 8];    // 32 KB  A-frags of W2lo
    __shared__ __align__(16) f16 wfcL [2 * 2 * 64 * 8];    // 4 KB   A-frags of Wfc (f16)
    __shared__ __align__(16) f16 hhiB[4 * 16 * 264];       // 33 KB  per-PAIR h-hi
    __shared__ __align__(16) f16 hloB[4 * 16 * 264];       // 33 KB  per-PAIR h-lo
    __shared__ __align__(16) f16 khiB[4 * 16 * 72];        // 9 KB   per-PAIR k-hi
    __shared__ __align__(16) f16 kloB[4 * 16 * 72];        // 9 KB   per-PAIR k-lo

    const int tid  = (int)threadIdx.x;
    const int wid  = tid >> 6;
    const int lane = tid & 63;
    const int q    = lane >> 4;     // quad 0..3
    const int c    = lane & 15;     // lane-in-16 (batch row within tile)
    const int pair = wid >> 1;      // 0..3 : which 16-row group
    const int half = wid & 1;       // 0..1 : which half of H / D work
    const int R0   = (int)blockIdx.x * 64 + pair * 16;
    const int jt0  = half * 8;      // GEMM1 H-tile range [jt0, jt0+8)
    const int dt0  = half * 2;      // GEMM2 D-tile range [dt0, dt0+2)

    f16* __restrict__ hhi = &hhiB[pair * 16 * 264];
    f16* __restrict__ hlo = &hloB[pair * 16 * 264];
    f16* __restrict__ khi = &khiB[pair * 16 * 72];
    f16* __restrict__ klo = &kloB[pair * 16 * 72];

    // ---------------- hi-weight A-fragments in registers (AGPR-friendly) ----
    // A-layout (16x16x32): lane holds A[m = tile*16 + c][k = ks*32 + q*8 + j]
    f16x8 w1a[8][2];    // W1T hi, jt = jt0 + j
#pragma unroll
    for (int j = 0; j < 8; ++j)
#pragma unroll
        for (int ks = 0; ks < 2; ++ks)
#pragma unroll
            for (int jj = 0; jj < 8; ++jj)
                w1a[j][ks][jj] = (f16)W1[(ks * 32 + q * 8 + jj) * 256 + (jt0 + j) * 16 + c];

    f16x8 w2a[2][8];    // W2T hi, dt = dt0 + d
#pragma unroll
    for (int d = 0; d < 2; ++d)
#pragma unroll
        for (int ks = 0; ks < 8; ++ks)
#pragma unroll
            for (int jj = 0; jj < 8; ++jj)
                w2a[d][ks][jj] = (f16)W2[(ks * 32 + q * 8 + jj) * 64 + (dt0 + d) * 16 + c];

    // ---------------- lo-weight A-fragments -> LDS (split across 8 waves) ----
    for (int jr = 0; jr < 2; ++jr) {
        int jt = wid * 2 + jr;
        for (int ks = 0; ks < 2; ++ks)
            for (int j = 0; j < 8; ++j) {
                float w = W1[(ks * 32 + q * 8 + j) * 256 + jt * 16 + c];
                f16 hi = (f16)w;
                w1loL[((jt * 2 + ks) * 64 + lane) * 8 + j] = (f16)(w - (float)hi);
            }
    }
    {
        int dt = wid >> 1;
        for (int kr = 0; kr < 4; ++kr) {
            int ks = (wid & 1) * 4 + kr;
            for (int j = 0; j < 8; ++j) {
                float w = W2[(ks * 32 + q * 8 + j) * 64 + dt * 16 + c];
                f16 hi = (f16)w;
                w2loL[((dt * 8 + ks) * 64 + lane) * 8 + j] = (f16)(w - (float)hi);
            }
        }
    }
    if (wid == 0)
        for (int ot = 0; ot < 2; ++ot)
            for (int ks = 0; ks < 2; ++ks)
                for (int j = 0; j < 8; ++j)
                    wfcL[((ot * 2 + ks) * 64 + lane) * 8 + j] =
                        (f16)Wfc[(ks * 32 + q * 8 + j) * 32 + ot * 16 + c];
    __syncthreads();   // weights become read-only after this

    // biases (persistent; b1 only needed at init)
    f32x4 b2v[2], bfcv;
#pragma unroll
    for (int d = 0; d < 2; ++d)
#pragma unroll
        for (int r = 0; r < 4; ++r) b2v[d][r] = b2[(dt0 + d) * 16 + 4 * q + r];
#pragma unroll
    for (int r = 0; r < 4; ++r) bfcv[r] = bfc[half * 16 + 4 * q + r];

    // ---------------- init from y0 (split hi+lo) ----------------
    f16x8 y0hi[2], y0lo[2];
#pragma unroll
    for (int ks = 0; ks < 2; ++ks)
#pragma unroll
        for (int j = 0; j < 8; ++j) {
            float v = y0g[(R0 + c) * 64 + ks * 32 + q * 8 + j];
            f16 hi = (f16)v;
            y0hi[ks][j] = hi;
            y0lo[ks][j] = (f16)(v - (float)hi);
        }

    f32x4 P1[8];
#pragma unroll
    for (int j = 0; j < 8; ++j) {
        f32x4 cc;
#pragma unroll
        for (int r = 0; r < 4; ++r) cc[r] = b1[(jt0 + j) * 16 + 4 * q + r];
#pragma unroll
        for (int ks = 0; ks < 2; ++ks) {
            f16x8 alo = *reinterpret_cast<const f16x8*>(&w1loL[(((jt0 + j) * 2 + ks) * 64 + lane) * 8]);
            cc = MFMA(w1a[j][ks], y0hi[ks], cc);
            cc = MFMA(w1a[j][ks], y0lo[ks], cc);
            cc = MFMA(alo,        y0hi[ks], cc);
        }
        P1[j] = cc;
    }
    // fc of y0: this wave produces output tile ot = half
    f32x4 pfc;
    {
        f32x4 z = {0.f, 0.f, 0.f, 0.f};
#pragma unroll
        for (int ks = 0; ks < 2; ++ks) {
            f16x8 wa = *reinterpret_cast<const f16x8*>(&wfcL[((half * 2 + ks) * 64 + lane) * 8]);
            z = MFMA(wa, y0hi[ks], z);
            z = MFMA(wa, y0lo[ks], z);
        }
        pfc = z;
    }
    {
        f32x4 v = pfc + bfcv;
        *reinterpret_cast<f32x4*>(&out[(size_t)(R0 + c) * 32 + half * 16 + 4 * q]) = v;
    }

    f32x4 ksum[2], dy[2];
#pragma unroll
    for (int d = 0; d < 2; ++d) dy[d] = f32x4{0.f, 0.f, 0.f, 0.f};

    // ---- bootstrap: h1 = tanh(P1) for this wave's jt half -> pair LDS ----
#pragma unroll
    for (int j = 0; j < 8; ++j) {
        float t0 = fast_tanh(P1[j][0]), t1 = fast_tanh(P1[j][1]);
        float t2 = fast_tanh(P1[j][2]), t3 = fast_tanh(P1[j][3]);
        f16x4 hv, lv;
        split4(t0, t1, t2, t3, &hv, &lv);
        *reinterpret_cast<f16x4*>(&hhi[c * 264 + (jt0 + j) * 16 + 4 * q]) = hv;
        *reinterpret_cast<f16x4*>(&hlo[c * 264 + (jt0 + j) * 16 + 4 * q]) = lv;
    }
    __syncthreads();

    float hh = 0.f, ch = 0.f, c6 = 0.f;

    // GEMM2half (D-split): k[dt0..dt0+1] = hhi@W2hi + hlo@W2hi + hhi@W2lo + b2
    // over FULL H (pair-shared h). ksum accumulate; split k (or c6*ksum) -> LDS.
    auto gemm2half = [&](float w, bool first, bool last) {
        f32x4 ka[2];
#pragma unroll
        for (int d = 0; d < 2; ++d) ka[d] = b2v[d];
#pragma unroll
        for (int ks = 0; ks < 8; ++ks) {
            f16x8 bhi = *reinterpret_cast<const f16x8*>(&hhi[c * 264 + ks * 32 + q * 8]);
            f16x8 blo = *reinterpret_cast<const f16x8*>(&hlo[c * 264 + ks * 32 + q * 8]);
#pragma unroll
            for (int d = 0; d < 2; ++d) {
                f16x8 alo = *reinterpret_cast<const f16x8*>(&w2loL[(((dt0 + d) * 8 + ks) * 64 + lane) * 8]);
                ka[d] = MFMA(w2a[d][ks], bhi, ka[d]);
                ka[d] = MFMA(w2a[d][ks], blo, ka[d]);
                ka[d] = MFMA(alo,        bhi, ka[d]);
            }
        }
#pragma unroll
        for (int d = 0; d < 2; ++d) {
            if (first)      ksum[d] = ka[d];
            else            ksum[d] += ka[d] * w;
            f32x4 kv;
            if (!last) {
                kv = ka[d];
            } else {
                kv = ksum[d] * c6;
                dy[d] += kv;
            }
            f16x4 hv, lv;
            split4(kv[0], kv[1], kv[2], kv[3], &hv, &lv);
            *reinterpret_cast<f16x4*>(&khi[c * 72 + (dt0 + d) * 16 + 4 * q]) = hv;
            *reinterpret_cast<f16x4*>(&klo[c * 72 + (dt0 + d) * 16 + 4 * q]) = lv;
        }
        __syncthreads();
    };

    // GEMM1half (H-split): per j in this wave's jt half: z = W1T@k (full D),
    // then a = P1 + carg*z (or final: P1 += z; a = P1), tanh, split -> pair h.
    auto gemm1half = [&](float carg, bool fin) {
        f16x8 kh0 = *reinterpret_cast<const f16x8*>(&khi[c * 72 + q * 8]);
        f16x8 kh1 = *reinterpret_cast<const f16x8*>(&khi[c * 72 + 32 + q * 8]);
        f16x8 kl0 = *reinterpret_cast<const f16x8*>(&klo[c * 72 + q * 8]);
        f16x8 kl1 = *reinterpret_cast<const f16x8*>(&klo[c * 72 + 32 + q * 8]);
#pragma unroll
        for (int j = 0; j < 8; ++j) {
            int jt = jt0 + j;
            f16x8 a0 = *reinterpret_cast<const f16x8*>(&w1loL[((jt * 2 + 0) * 64 + lane) * 8]);
            f16x8 a1 = *reinterpret_cast<const f16x8*>(&w1loL[((jt * 2 + 1) * 64 + lane) * 8]);
            f32x4 z = {0.f, 0.f, 0.f, 0.f};
            z = MFMA(w1a[j][0], kh0, z);
            z = MFMA(w1a[j][0], kl0, z);
            z = MFMA(a0,        kh0, z);
            z = MFMA(w1a[j][1], kh1, z);
            z = MFMA(w1a[j][1], kl1, z);
            z = MFMA(a1,        kh1, z);
            float a0f, a1f, a2f, a3f;
            if (fin) {
                P1[j] += z;
                a0f = P1[j][0]; a1f = P1[j][1]; a2f = P1[j][2]; a3f = P1[j][3];
            } else {
                a0f = __builtin_fmaf(carg, z[0], P1[j][0]);
                a1f = __builtin_fmaf(carg, z[1], P1[j][1]);
                a2f = __builtin_fmaf(carg, z[2], P1[j][2]);
                a3f = __builtin_fmaf(carg, z[3], P1[j][3]);
            }
            float t0 = fast_tanh(a0f), t1 = fast_tanh(a1f);
            float t2 = fast_tanh(a2f), t3 = fast_tanh(a3f);
            f16x4 hv, lv;
            split4(t0, t1, t2, t3, &hv, &lv);
            *reinterpret_cast<f16x4*>(&hhi[c * 264 + jt * 16 + 4 * q]) = hv;
            *reinterpret_cast<f16x4*>(&hlo[c * 264 + jt * 16 + 4 * q]) = lv;
        }
        __syncthreads();
    };

#pragma unroll 1
    for (int ti = 0; ti < 49; ++ti) {
        float dtv = tg[ti + 1] - tg[ti];
        hh = dtv * 0.125f;
        ch = 0.5f * hh;
        c6 = hh * (1.0f / 6.0f);
#pragma unroll 1
        for (int sub = 0; sub < 8; ++sub) {
            gemm2half(1.0f, true,  false);  // k1;       ksum  = k1
            gemm1half(ch, false);           // h2 = tanh(P1 + ch*U1)
            gemm2half(2.0f, false, false);  // k2;       ksum += 2*k2
            gemm1half(ch, false);           // h3
            gemm2half(2.0f, false, false);  // k3;       ksum += 2*k3
            gemm1half(hh, false);           // h4
            gemm2half(1.0f, false, true);   // k4; ksum += k4; kv = c6*ksum; dy += kv
            gemm1half(0.0f, true);          // P1 += W1T@kv; h1' = tanh(P1)
        }
        // ---- interval epilogue: pfc += dy @ Wfc (dy split hi+lo, pair-merged) ----
#pragma unroll
        for (int d = 0; d < 2; ++d) {
            f16x4 hv, lv;
            split4(dy[d][0], dy[d][1], dy[d][2], dy[d][3], &hv, &lv);
            *reinterpret_cast<f16x4*>(&khi[c * 72 + (dt0 + d) * 16 + 4 * q]) = hv;
            *reinterpret_cast<f16x4*>(&klo[c * 72 + (dt0 + d) * 16 + 4 * q]) = lv;
            dy[d] = f32x4{0.f, 0.f, 0.f, 0.f};
        }
        __syncthreads();
        {
            f16x8 dh0 = *reinterpret_cast<const f16x8*>(&khi[c * 72 + q * 8]);
            f16x8 dh1 = *reinterpret_cast<const f16x8*>(&khi[c * 72 + 32 + q * 8]);
            f16x8 dl0 = *reinterpret_cast<const f16x8*>(&klo[c * 72 + q * 8]);
            f16x8 dl1 = *reinterpret_cast<const f16x8*>(&klo[c * 72 + 32 + q * 8]);
            f16x8 wa0 = *reinterpret_cast<const f16x8*>(&wfcL[((half * 2 + 0) * 64 + lane) * 8]);
            f16x8 wa1 = *reinterpret_cast<const f16x8*>(&wfcL[((half * 2 + 1) * 64 + lane) * 8]);
            pfc = MFMA(wa0, dh0, pfc);
            pfc = MFMA(wa0, dl0, pfc);
            pfc = MFMA(wa1, dh1, pfc);
            pfc = MFMA(wa1, dl1, pfc);
        }
        __syncthreads();   // epilogue k-reads drained before next interval's k-writes
        size_t base = (size_t)(ti + 1) * (16384 * 32);
        {
            f32x4 v = pfc + bfcv;
            *reinterpret_cast<f32x4*>(&out[base + (size_t)(R0 + c) * 32 + half * 16 + 4 * q]) = v;
        }
    }
}

extern "C" void kernel_launch(void* const* d_in, const int* in_sizes, int n_in,
                              void* d_out, int out_size, void* d_ws, size_t ws_size,
                              hipStream_t stream) {
    (void)in_sizes; (void)n_in; (void)d_ws; (void)ws_size; (void)out_size;
    const float* y0  = (const float*)d_in[0];
    const float* t   = (const float*)d_in[1];
    const float* W1  = (const float*)d_in[2];
    const float* b1  = (const float*)d_in[3];
    const float* W2  = (const float*)d_in[4];
    const float* b2  = (const float*)d_in[5];
    const float* Wfc = (const float*)d_in[6];
    const float* bfc = (const float*)d_in[7];
    float* out = (float*)d_out;
    // 256 blocks x 512 threads: 8 waves (4 row-pairs x 2 halves), 1 block/CU,
    // 2 waves/SIMD (LDS 152 KB; <=256 regs/wave via __launch_bounds__(512,2))
    node_fused<<<dim3(256), dim3(512), 0, stream>>>(y0, t, W1, b1, W2, b2, Wfc, bfc, out);
}